// Round 1
// baseline (235.515 us; speedup 1.0000x reference)
//
#include <hip/hip_runtime.h>
#include <hip/hip_bf16.h>

typedef __attribute__((ext_vector_type(8))) __bf16 bf16x8;
typedef __attribute__((ext_vector_type(4))) float f32x4;

#define LN2F 0.6931471805599453f

// ---- async global->LDS, 16B per lane, wave-uniform LDS base ----
__device__ __forceinline__ void gload16(const void* g, void* l) {
  __builtin_amdgcn_global_load_lds(
      (const __attribute__((address_space(1))) void*)g,
      (__attribute__((address_space(3))) void*)l,
      16, 0, 0);
}

// ---------------------------------------------------------------------------
// Layouts (all bf16):
//   Xb: A tiles, tile id = (row>>7)*16 + (k>>6); tile = 128 rows x 64 k elems
//       elem offset in tile = r*64 + ((s*8) ^ ((r&7)<<3)), r=row&127, s=(k&63)>>3
//   Kb: B^T tiles, tile id = (h>>7)*16 + (i>>6); same in-tile layout with
//       row = h&127 (output col), k = i (reduction).
// The XOR swizzle (16B granules XOR'd by row&7) makes the MFMA-fragment
// ds_read_b128 at row-stride 128B effectively conflict-free (2-way max).
// global_load_lds streams each 16KB tile linearly, so the swizzle is baked
// into the *global* layout (both-sides-or-neither rule).
// ---------------------------------------------------------------------------

// convert x (f32 [4096][1024]) -> Xb bf16 tiled+swizzled; also out[b] += vb * rowsum(x[b])
__global__ void k_cvt_x(const float* __restrict__ x, const float* __restrict__ vbias,
                        __bf16* __restrict__ Xb, float* __restrict__ out) {
  int t = threadIdx.x;
  int row = blockIdx.x * 2 + (t >> 7);   // 2 rows per block
  int slot = t & 127;                    // 128 slots of 8 elems = 1024
  const float4* xp = (const float4*)(x + (size_t)row * 1024 + (size_t)slot * 8);
  float4 v0 = xp[0], v1 = xp[1];
  bf16x8 h;
  h[0] = (__bf16)v0.x; h[1] = (__bf16)v0.y; h[2] = (__bf16)v0.z; h[3] = (__bf16)v0.w;
  h[4] = (__bf16)v1.x; h[5] = (__bf16)v1.y; h[6] = (__bf16)v1.z; h[7] = (__bf16)v1.w;
  int kt = slot >> 3, si = slot & 7;
  int r = row & 127;
  size_t off = ((size_t)((row >> 7) * 16 + kt)) * 8192 + (size_t)r * 64 + ((si * 8) ^ ((r & 7) << 3));
  *(bf16x8*)(Xb + off) = h;
  float s = v0.x + v0.y + v0.z + v0.w + v1.x + v1.y + v1.z + v1.w;
  #pragma unroll
  for (int m = 32; m; m >>= 1) s += __shfl_down(s, m);
  if ((t & 63) == 0) atomicAdd(out + row, vbias[0] * s);
}

// W [1024][16] -> Wt [16][1024] (f32) so the expand gather is contiguous
__global__ void k_transpose_w(const float* __restrict__ W, float* __restrict__ Wt) {
  int g = blockIdx.x * 256 + threadIdx.x;   // 16384
  int i = g >> 4, j = g & 15;
  Wt[j * 1024 + i] = W[g];
}

// expand circulant kernel: Kb^T[h][i] = Wt[h>>10][(i + (h&1023)) & 1023]
__global__ void k_expand(const float* __restrict__ Wt, __bf16* __restrict__ Kb) {
  int gid = blockIdx.x * 256 + threadIdx.x;   // 16384*128 = 2M slots
  int h = gid >> 7;
  int slot = gid & 127;
  int kt = slot >> 3, si = slot & 7;
  int j = h >> 10, kh = h & 1023;
  int i0 = kt * 64 + si * 8;
  const float* wj = Wt + j * 1024;
  bf16x8 v;
  #pragma unroll
  for (int e = 0; e < 8; ++e) v[e] = (__bf16)wj[(i0 + e + kh) & 1023];
  int r = h & 127;
  size_t off = ((size_t)((h >> 7) * 16 + kt)) * 8192 + (size_t)r * 64 + ((si * 8) ^ ((r & 7) << 3));
  *(bf16x8*)(Kb + off) = v;
}

// fused GEMM (bf16 MFMA) + bias + logcosh + row-reduce + atomicAdd
// grid: (128 n-tiles, 32 m-tiles), block 256 = 4 waves (2x2), each wave 64x64
__global__ __launch_bounds__(256, 2) void k_gemm_lc(
    const __bf16* __restrict__ Xb, const __bf16* __restrict__ Kb,
    const float* __restrict__ bsymm, float* __restrict__ out) {
  __shared__ __align__(16) __bf16 As[8192];
  __shared__ __align__(16) __bf16 Bs[8192];
  int nt = blockIdx.x, mt = blockIdx.y;
  int tid = threadIdx.x;
  int w = tid >> 6, lane = tid & 63;
  int wm = w >> 1, wn = w & 1;
  int lr = lane & 15, lk = lane >> 4;

  f32x4 acc[4][4] = {};

  const __bf16* Ab = Xb + (size_t)mt * 16 * 8192;
  const __bf16* Bb = Kb + (size_t)nt * 16 * 8192;

  for (int kt = 0; kt < 16; ++kt) {
    __syncthreads();   // previous iter's ds_reads done before overwrite
    const __bf16* ga = Ab + kt * 8192 + w * 2048 + lane * 8;
    const __bf16* gb = Bb + kt * 8192 + w * 2048 + lane * 8;
    __bf16* la = As + w * 2048;
    __bf16* lb = Bs + w * 2048;
    #pragma unroll
    for (int c = 0; c < 4; ++c) {
      gload16(ga + c * 512, la + c * 512);
      gload16(gb + c * 512, lb + c * 512);
    }
    __syncthreads();   // compiler drains vmcnt(0) before barrier

    bf16x8 af[4][2], bfr[4][2];
    #pragma unroll
    for (int m = 0; m < 4; ++m) {
      #pragma unroll
      for (int kh = 0; kh < 2; ++kh) {
        int rowA = wm * 64 + m * 16 + lr;
        int keA = (kh * 32 + lk * 8) ^ ((rowA & 7) << 3);
        af[m][kh] = *(const bf16x8*)(As + rowA * 64 + keA);
        int rowB = wn * 64 + m * 16 + lr;
        int keB = (kh * 32 + lk * 8) ^ ((rowB & 7) << 3);
        bfr[m][kh] = *(const bf16x8*)(Bs + rowB * 64 + keB);
      }
    }
    #pragma unroll
    for (int m = 0; m < 4; ++m)
      #pragma unroll
      for (int n = 0; n < 4; ++n)
        #pragma unroll
        for (int kh = 0; kh < 2; ++kh)
          acc[m][n] = __builtin_amdgcn_mfma_f32_16x16x32_bf16(af[m][kh], bfr[n][kh], acc[m][n], 0, 0, 0);
  }

  // epilogue: bias + logcosh + reduce over this wave's 64 columns
  float bias = bsymm[nt >> 3];   // 128 cols per block all in one j-slab
  float rs[4][4];
  #pragma unroll
  for (int m = 0; m < 4; ++m)
    #pragma unroll
    for (int i = 0; i < 4; ++i) rs[m][i] = 0.f;

  #pragma unroll
  for (int m = 0; m < 4; ++m)
    #pragma unroll
    for (int n = 0; n < 4; ++n)
      #pragma unroll
      for (int i = 0; i < 4; ++i) {
        float v = acc[m][n][i] + bias;
        float ax = fabsf(v);
        rs[m][i] += ax + __logf(1.0f + __expf(-2.0f * ax));
      }

  #pragma unroll
  for (int m = 0; m < 4; ++m)
    #pragma unroll
    for (int i = 0; i < 4; ++i) {
      float s = rs[m][i] - 4.0f * LN2F;
      s += __shfl_xor(s, 1);
      s += __shfl_xor(s, 2);
      s += __shfl_xor(s, 4);
      s += __shfl_xor(s, 8);
      if (lr == 0)
        atomicAdd(out + mt * 128 + wm * 64 + m * 16 + lk * 4 + i, s);
    }
}

// fallback if workspace is too small: correct but slow
__global__ void k_naive(const float* __restrict__ x, const float* __restrict__ W,
                        const float* __restrict__ bs, const float* __restrict__ vb,
                        float* __restrict__ out) {
  int b = blockIdx.x;
  __shared__ float xs[1024];
  __shared__ float red[256];
  int t = threadIdx.x;
  float xsum = 0.f;
  for (int i = t; i < 1024; i += 256) { float v = x[(size_t)b * 1024 + i]; xs[i] = v; xsum += v; }
  __syncthreads();
  float tot = vb[0] * xsum;
  for (int h = t; h < 16384; h += 256) {
    int j = h >> 10, kh = h & 1023;
    float a = bs[j];
    for (int i = 0; i < 1024; ++i) a += xs[i] * W[((i + kh) & 1023) * 16 + j];
    float ax = fabsf(a);
    tot += ax + __logf(1.f + __expf(-2.f * ax)) - LN2F;
  }
  red[t] = tot;
  __syncthreads();
  for (int s2 = 128; s2; s2 >>= 1) { if (t < s2) red[t] += red[t + s2]; __syncthreads(); }
  if (t == 0) out[b] = red[0];
}

extern "C" void kernel_launch(void* const* d_in, const int* in_sizes, int n_in,
                              void* d_out, int out_size, void* d_ws, size_t ws_size,
                              hipStream_t stream) {
  const float* x  = (const float*)d_in[0];   // [4096,1024]
  const float* W  = (const float*)d_in[1];   // [1024,16]
  const float* bs = (const float*)d_in[2];   // [16]
  const float* vb = (const float*)d_in[3];   // [1]
  float* out = (float*)d_out;                // [4096]

  hipMemsetAsync(d_out, 0, (size_t)out_size * sizeof(float), stream);

  size_t need = ((size_t)8 << 20) + ((size_t)32 << 20) + ((size_t)64 << 10);
  if (ws_size < need) {
    k_naive<<<4096, 256, 0, stream>>>(x, W, bs, vb, out);
    return;
  }

  __bf16* Xb = (__bf16*)d_ws;                                   // 8 MB
  __bf16* Kb = (__bf16*)((char*)d_ws + ((size_t)8 << 20));      // 32 MB
  float*  Wt = (float*)((char*)d_ws + ((size_t)40 << 20));      // 64 KB

  k_cvt_x<<<2048, 256, 0, stream>>>(x, vb, Xb, out);
  k_transpose_w<<<64, 256, 0, stream>>>(W, Wt);
  k_expand<<<8192, 256, 0, stream>>>(Wt, Kb);

  dim3 grid(128, 32);
  k_gemm_lc<<<grid, 256, 0, stream>>>(Xb, Kb, bs, out);
}

// Round 2
// 234.639 us; speedup vs baseline: 1.0037x; 1.0037x over previous
//
#include <hip/hip_runtime.h>
#include <hip/hip_bf16.h>

typedef __attribute__((ext_vector_type(8))) __bf16 bf16x8;
typedef __attribute__((ext_vector_type(4))) float f32x4;

#define LN2F 0.6931471805599453f

__device__ __forceinline__ void gload16(const void* g, void* l) {
  __builtin_amdgcn_global_load_lds(
      (const __attribute__((address_space(1))) void*)g,
      (__attribute__((address_space(3))) void*)l,
      16, 0, 0);
}

// ---------------------------------------------------------------------------
// Global bf16 layouts (produced by k_cvt_x / k_expand, same as round 1):
//   Xb: 32 mtiles x 16 ktiles, tile = 128 rows x 64 k = 8192 elems, in-tile
//       elem off = r*64 + ((s*8) ^ ((r&7)<<3))   (16B-granule XOR swizzle)
//   Kb: 128 ntiles x 16 ktiles, same in-tile layout (rows = output cols).
// GEMM: 256x256x64 tiles, 512 thr = 8 waves (2M x 4N), per-wave 128x64,
// double-buffered 128KiB LDS, 4 phases/K-tile, counted-vmcnt pipeline.
// ---------------------------------------------------------------------------

__global__ void k_cvt_x(const float* __restrict__ x, const float* __restrict__ vbias,
                        __bf16* __restrict__ Xb, float* __restrict__ out) {
  int t = threadIdx.x;
  int row = blockIdx.x * 2 + (t >> 7);
  int slot = t & 127;
  const float4* xp = (const float4*)(x + (size_t)row * 1024 + (size_t)slot * 8);
  float4 v0 = xp[0], v1 = xp[1];
  bf16x8 h;
  h[0] = (__bf16)v0.x; h[1] = (__bf16)v0.y; h[2] = (__bf16)v0.z; h[3] = (__bf16)v0.w;
  h[4] = (__bf16)v1.x; h[5] = (__bf16)v1.y; h[6] = (__bf16)v1.z; h[7] = (__bf16)v1.w;
  int kt = slot >> 3, si = slot & 7;
  int r = row & 127;
  size_t off = ((size_t)((row >> 7) * 16 + kt)) * 8192 + (size_t)r * 64 + ((si * 8) ^ ((r & 7) << 3));
  *(bf16x8*)(Xb + off) = h;
  float s = v0.x + v0.y + v0.z + v0.w + v1.x + v1.y + v1.z + v1.w;
  #pragma unroll
  for (int m = 32; m; m >>= 1) s += __shfl_down(s, m);
  if ((t & 63) == 0) atomicAdd(out + row, vbias[0] * s);
}

__global__ void k_transpose_w(const float* __restrict__ W, float* __restrict__ Wt) {
  int g = blockIdx.x * 256 + threadIdx.x;
  int i = g >> 4, j = g & 15;
  Wt[j * 1024 + i] = W[g];
}

__global__ void k_expand(const float* __restrict__ Wt, __bf16* __restrict__ Kb) {
  int gid = blockIdx.x * 256 + threadIdx.x;
  int h = gid >> 7;
  int slot = gid & 127;
  int kt = slot >> 3, si = slot & 7;
  int j = h >> 10, kh = h & 1023;
  int i0 = kt * 64 + si * 8;
  const float* wj = Wt + j * 1024;
  bf16x8 v;
  #pragma unroll
  for (int e = 0; e < 8; ++e) v[e] = (__bf16)wj[(i0 + e + kh) & 1023];
  int r = h & 127;
  size_t off = ((size_t)((h >> 7) * 16 + kt)) * 8192 + (size_t)r * 64 + ((si * 8) ^ ((r & 7) << 3));
  *(bf16x8*)(Kb + off) = v;
}

// stage one 256x64 A-tile + 256x64 B-tile (64KB) into buffer `buf`
__device__ __forceinline__ void stage_tile(const __bf16* __restrict__ Xb,
                                           const __bf16* __restrict__ Kb,
                                           __bf16* As, __bf16* Bs, int buf,
                                           int by, int bx, int kt, int w, int lane) {
  #pragma unroll
  for (int h = 0; h < 2; ++h) {
    const __bf16* ga = Xb + ((size_t)((2 * by + h) * 16 + kt)) * 8192 + w * 512 + lane * 8;
    __bf16* la = As + (buf * 2 + h) * 8192 + w * 512;
    gload16(ga, la);
    gload16(ga + 4096, la + 4096);
    const __bf16* gb = Kb + ((size_t)((2 * bx + h) * 16 + kt)) * 8192 + w * 512 + lane * 8;
    __bf16* lb = Bs + (buf * 2 + h) * 8192 + w * 512;
    gload16(gb, lb);
    gload16(gb + 4096, lb + 4096);
  }
}

__global__ __launch_bounds__(512, 2) void k_gemm_lc2(
    const __bf16* __restrict__ Xb, const __bf16* __restrict__ Kb,
    const float* __restrict__ bsymm, float* __restrict__ out) {
  __shared__ __align__(16) __bf16 As[32768];   // 2 buf x 2 half x 8192
  __shared__ __align__(16) __bf16 Bs[32768];

  // XCD-aware swizzle: 1024 wgs, 8 XCDs, chunk = 128; consecutive logical ids
  // share the B-panel (512KB, L2-resident)
  int hw = blockIdx.x;
  int wg = (hw & 7) * 128 + (hw >> 3);
  int by = wg & 15;        // M super-tile (rows by*256..)
  int bx = wg >> 4;        // N super-tile (cols bx*256..)
  int tid = threadIdx.x;
  int w = tid >> 6, lane = tid & 63;
  int wm = w >> 2, wn = w & 3;     // 2 x 4 waves
  int lr = lane & 15, lk = lane >> 4;

  f32x4 acc[8][4] = {};

  stage_tile(Xb, Kb, As, Bs, 0, by, bx, 0, w, lane);
  asm volatile("s_waitcnt vmcnt(0)" ::: "memory");
  __builtin_amdgcn_s_barrier();
  __builtin_amdgcn_sched_barrier(0);

  for (int t = 0; t < 16; ++t) {
    int cur = t & 1;
    const __bf16* Ah = As + (cur * 2 + wm) * 8192;        // wave's A half (128x64)
    const __bf16* Bh = Bs + (cur * 2 + (wn >> 1)) * 8192; // wave's B half

    #pragma unroll
    for (int p = 0; p < 4; ++p) {
      const int qm = p & 1, qn = p >> 1;   // 64x32 quadrant of wave's 128x64
      bf16x8 af[4][2], bf[2][2];
      #pragma unroll
      for (int m = 0; m < 4; ++m) {
        int r = qm * 64 + m * 16 + lr;
        #pragma unroll
        for (int kh = 0; kh < 2; ++kh)
          af[m][kh] = *(const bf16x8*)(Ah + r * 64 + (((kh * 4 + lk) * 8) ^ ((r & 7) << 3)));
      }
      #pragma unroll
      for (int n = 0; n < 2; ++n) {
        int r = (wn & 1) * 64 + qn * 32 + n * 16 + lr;
        #pragma unroll
        for (int kh = 0; kh < 2; ++kh)
          bf[n][kh] = *(const bf16x8*)(Bh + r * 64 + (((kh * 4 + lk) * 8) ^ ((r & 7) << 3)));
      }
      if (p == 0 && t < 15)
        stage_tile(Xb, Kb, As, Bs, cur ^ 1, by, bx, t + 1, w, lane);  // in flight across phases

      __builtin_amdgcn_s_barrier();
      __builtin_amdgcn_s_setprio(1);
      #pragma unroll
      for (int m = 0; m < 4; ++m)
        #pragma unroll
        for (int n = 0; n < 2; ++n)
          #pragma unroll
          for (int kh = 0; kh < 2; ++kh)
            acc[qm * 4 + m][qn * 2 + n] = __builtin_amdgcn_mfma_f32_16x16x32_bf16(
                af[m][kh], bf[n][kh], acc[qm * 4 + m][qn * 2 + n], 0, 0, 0);
      __builtin_amdgcn_s_setprio(0);
      if (p == 3 && t < 15)
        asm volatile("s_waitcnt vmcnt(0)" ::: "memory");  // next tile landed (issued 4 phases ago)
      __builtin_amdgcn_s_barrier();
      __builtin_amdgcn_sched_barrier(0);
    }
  }

  // epilogue: bias + logcosh + reduce over wave's 64 cols, atomicAdd per row
  float bias = bsymm[bx >> 2];   // 256 cols per block lie in one j-slab
  #pragma unroll
  for (int m = 0; m < 8; ++m) {
    float rs[4] = {0.f, 0.f, 0.f, 0.f};
    #pragma unroll
    for (int n = 0; n < 4; ++n)
      #pragma unroll
      for (int i = 0; i < 4; ++i) {
        float v = acc[m][n][i] + bias;
        float ax = fabsf(v);
        rs[i] += ax + __logf(1.0f + __expf(-2.0f * ax));
      }
    #pragma unroll
    for (int i = 0; i < 4; ++i) {
      float s = rs[i] - 4.0f * LN2F;
      s += __shfl_xor(s, 1);
      s += __shfl_xor(s, 2);
      s += __shfl_xor(s, 4);
      s += __shfl_xor(s, 8);
      if (lr == 0)
        atomicAdd(out + by * 256 + wm * 128 + m * 16 + lk * 4 + i, s);
    }
  }
}

// fallback if workspace is too small: correct but slow
__global__ void k_naive(const float* __restrict__ x, const float* __restrict__ W,
                        const float* __restrict__ bs, const float* __restrict__ vb,
                        float* __restrict__ out) {
  int b = blockIdx.x;
  __shared__ float xs[1024];
  __shared__ float red[256];
  int t = threadIdx.x;
  float xsum = 0.f;
  for (int i = t; i < 1024; i += 256) { float v = x[(size_t)b * 1024 + i]; xs[i] = v; xsum += v; }
  __syncthreads();
  float tot = vb[0] * xsum;
  for (int h = t; h < 16384; h += 256) {
    int j = h >> 10, kh = h & 1023;
    float a = bs[j];
    for (int i = 0; i < 1024; ++i) a += xs[i] * W[((i + kh) & 1023) * 16 + j];
    float ax = fabsf(a);
    tot += ax + __logf(1.f + __expf(-2.f * ax)) - LN2F;
  }
  red[t] = tot;
  __syncthreads();
  for (int s2 = 128; s2; s2 >>= 1) { if (t < s2) red[t] += red[t + s2]; __syncthreads(); }
  if (t == 0) out[b] = red[0];
}

extern "C" void kernel_launch(void* const* d_in, const int* in_sizes, int n_in,
                              void* d_out, int out_size, void* d_ws, size_t ws_size,
                              hipStream_t stream) {
  const float* x  = (const float*)d_in[0];
  const float* W  = (const float*)d_in[1];
  const float* bs = (const float*)d_in[2];
  const float* vb = (const float*)d_in[3];
  float* out = (float*)d_out;

  hipMemsetAsync(d_out, 0, (size_t)out_size * sizeof(float), stream);

  size_t need = ((size_t)8 << 20) + ((size_t)32 << 20) + ((size_t)64 << 10);
  if (ws_size < need) {
    k_naive<<<4096, 256, 0, stream>>>(x, W, bs, vb, out);
    return;
  }

  __bf16* Xb = (__bf16*)d_ws;
  __bf16* Kb = (__bf16*)((char*)d_ws + ((size_t)8 << 20));
  float*  Wt = (float*)((char*)d_ws + ((size_t)40 << 20));

  k_cvt_x<<<2048, 256, 0, stream>>>(x, vb, Xb, out);
  k_transpose_w<<<64, 256, 0, stream>>>(W, Wt);
  k_expand<<<8192, 256, 0, stream>>>(Wt, Kb);

  k_gemm_lc2<<<1024, 512, 0, stream>>>(Xb, Kb, bs, out);
}

// Round 3
// 213.261 us; speedup vs baseline: 1.1044x; 1.1002x over previous
//
#include <hip/hip_runtime.h>
#include <hip/hip_bf16.h>

typedef __attribute__((ext_vector_type(8))) __bf16 bf16x8;
typedef __attribute__((ext_vector_type(4))) float f32x4;

#define LN2F 0.6931471805599453f

__device__ __forceinline__ void gload16(const void* g, void* l) {
  __builtin_amdgcn_global_load_lds(
      (const __attribute__((address_space(1))) void*)g,
      (__attribute__((address_space(3))) void*)l,
      16, 0, 0);
}

// ---------------------------------------------------------------------------
// Global bf16 layouts:
//   Xb: 32 mtiles x 16 ktiles, tile = 128 rows x 64 k = 8192 elems, in-tile
//       elem off = r*64 + ((s*8) ^ ((r&7)<<3))   (16B-granule XOR swizzle)
//   Kb: 128 ntiles x 16 ktiles, same in-tile layout (rows = output cols).
// GEMM: 256x256x64 tiles, 512 thr = 8 waves (2M x 4N), per-wave 128x64.
// Each fragment is ds_read exactly ONCE per K-tile (24 KB/wave/K-tile =
// 384 B/MFMA -> under the ~256 B/cy/CU LDS ceiling at ~80% MFMA rate).
// One counted-vmcnt stage pipeline per K-tile, 2 barriers/K-tile.
// ---------------------------------------------------------------------------

__global__ void k_cvt_x(const float* __restrict__ x, const float* __restrict__ vbias,
                        __bf16* __restrict__ Xb, float* __restrict__ out) {
  int t = threadIdx.x;
  int row = blockIdx.x * 2 + (t >> 7);
  int slot = t & 127;
  const float4* xp = (const float4*)(x + (size_t)row * 1024 + (size_t)slot * 8);
  float4 v0 = xp[0], v1 = xp[1];
  bf16x8 h;
  h[0] = (__bf16)v0.x; h[1] = (__bf16)v0.y; h[2] = (__bf16)v0.z; h[3] = (__bf16)v0.w;
  h[4] = (__bf16)v1.x; h[5] = (__bf16)v1.y; h[6] = (__bf16)v1.z; h[7] = (__bf16)v1.w;
  int kt = slot >> 3, si = slot & 7;
  int r = row & 127;
  size_t off = ((size_t)((row >> 7) * 16 + kt)) * 8192 + (size_t)r * 64 + ((si * 8) ^ ((r & 7) << 3));
  *(bf16x8*)(Xb + off) = h;
  float s = v0.x + v0.y + v0.z + v0.w + v1.x + v1.y + v1.z + v1.w;
  #pragma unroll
  for (int m = 32; m; m >>= 1) s += __shfl_down(s, m);
  if ((t & 63) == 0) atomicAdd(out + row, vbias[0] * s);
}

// expand circulant: Kb^T[h][i] = W[(i + (h&1023)) & 1023][h>>10]  (W cache-resident)
__global__ void k_expand(const float* __restrict__ W, __bf16* __restrict__ Kb) {
  int gid = blockIdx.x * 256 + threadIdx.x;
  int h = gid >> 7;
  int slot = gid & 127;
  int kt = slot >> 3, si = slot & 7;
  int j = h >> 10, kh = h & 1023;
  int i0 = kt * 64 + si * 8;
  bf16x8 v;
  #pragma unroll
  for (int e = 0; e < 8; ++e) v[e] = (__bf16)W[((i0 + e + kh) & 1023) * 16 + j];
  int r = h & 127;
  size_t off = ((size_t)((h >> 7) * 16 + kt)) * 8192 + (size_t)r * 64 + ((si * 8) ^ ((r & 7) << 3));
  *(bf16x8*)(Kb + off) = v;
}

// stage one 256x64 A-tile + 256x64 B-tile (64KB) into buffer `buf` (8 loads/wave)
__device__ __forceinline__ void stage_tile(const __bf16* __restrict__ Xb,
                                           const __bf16* __restrict__ Kb,
                                           __bf16* As, __bf16* Bs, int buf,
                                           int by, int bx, int kt, int w, int lane) {
  #pragma unroll
  for (int h = 0; h < 2; ++h) {
    const __bf16* ga = Xb + ((size_t)((2 * by + h) * 16 + kt)) * 8192 + w * 512 + lane * 8;
    __bf16* la = As + (buf * 2 + h) * 8192 + w * 512;
    gload16(ga, la);
    gload16(ga + 4096, la + 4096);
    const __bf16* gb = Kb + ((size_t)((2 * bx + h) * 16 + kt)) * 8192 + w * 512 + lane * 8;
    __bf16* lb = Bs + (buf * 2 + h) * 8192 + w * 512;
    gload16(gb, lb);
    gload16(gb + 4096, lb + 4096);
  }
}

__global__ __launch_bounds__(512, 2) void k_gemm_lc3(
    const __bf16* __restrict__ Xb, const __bf16* __restrict__ Kb,
    const float* __restrict__ bsymm, float* __restrict__ out) {
  __shared__ __align__(16) __bf16 As[32768];   // 2 buf x 2 half x 8192
  __shared__ __align__(16) __bf16 Bs[32768];

  int hw = blockIdx.x;
  int wg = (hw & 7) * 128 + (hw >> 3);   // XCD-aware swizzle (1024 % 8 == 0)
  int by = wg & 15;
  int bx = wg >> 4;
  int tid = threadIdx.x;
  int w = tid >> 6, lane = tid & 63;
  int wm = w >> 2, wn = w & 3;
  int lr = lane & 15, lk = lane >> 4;

  f32x4 acc[8][4] = {};

  stage_tile(Xb, Kb, As, Bs, 0, by, bx, 0, w, lane);

  for (int t = 0; t < 16; ++t) {
    int cur = t & 1;
    if (t < 15) {
      stage_tile(Xb, Kb, As, Bs, cur ^ 1, by, bx, t + 1, w, lane);
      asm volatile("s_waitcnt vmcnt(8)" ::: "memory");   // drain stage(t), keep stage(t+1) in flight
    } else {
      asm volatile("s_waitcnt vmcnt(0)" ::: "memory");
    }
    __builtin_amdgcn_sched_barrier(0);
    __builtin_amdgcn_s_barrier();          // buf[cur] valid for all waves

    const __bf16* Ah = As + (cur * 2 + wm) * 8192;        // wave's 128x64 A half
    const __bf16* Bh = Bs + (cur * 2 + (wn >> 1)) * 8192; // wave's B half

    bf16x8 bfr[4][2];
    #pragma unroll
    for (int n = 0; n < 4; ++n) {
      int r = (wn & 1) * 64 + n * 16 + lr;
      #pragma unroll
      for (int kh = 0; kh < 2; ++kh)
        bfr[n][kh] = *(const bf16x8*)(Bh + r * 64 + (((kh * 4 + lk) * 8) ^ ((r & 7) << 3)));
    }
    #pragma unroll
    for (int ph = 0; ph < 2; ++ph) {
      bf16x8 af[4][2];
      #pragma unroll
      for (int m = 0; m < 4; ++m) {
        int r = ph * 64 + m * 16 + lr;
        #pragma unroll
        for (int kh = 0; kh < 2; ++kh)
          af[m][kh] = *(const bf16x8*)(Ah + r * 64 + (((kh * 4 + lk) * 8) ^ ((r & 7) << 3)));
      }
      __builtin_amdgcn_s_setprio(1);
      #pragma unroll
      for (int m = 0; m < 4; ++m)
        #pragma unroll
        for (int n = 0; n < 4; ++n)
          #pragma unroll
          for (int kh = 0; kh < 2; ++kh)
            acc[ph * 4 + m][n] = __builtin_amdgcn_mfma_f32_16x16x32_bf16(
                af[m][kh], bfr[n][kh], acc[ph * 4 + m][n], 0, 0, 0);
      __builtin_amdgcn_s_setprio(0);
    }

    asm volatile("s_waitcnt lgkmcnt(0)" ::: "memory");    // all my reads of buf[cur] done
    __builtin_amdgcn_sched_barrier(0);
    __builtin_amdgcn_s_barrier();          // everyone done reading buf[cur]
  }

  // epilogue: bias + logcosh + reduce over wave's 64 cols, atomicAdd per row
  float bias = bsymm[bx >> 2];
  #pragma unroll
  for (int m = 0; m < 8; ++m) {
    float rs[4] = {0.f, 0.f, 0.f, 0.f};
    #pragma unroll
    for (int n = 0; n < 4; ++n)
      #pragma unroll
      for (int i = 0; i < 4; ++i) {
        float v = acc[m][n][i] + bias;
        float ax = fabsf(v);
        rs[i] += ax + __logf(1.0f + __expf(-2.0f * ax));
      }
    #pragma unroll
    for (int i = 0; i < 4; ++i) {
      float s = rs[i] - 4.0f * LN2F;
      s += __shfl_xor(s, 1);
      s += __shfl_xor(s, 2);
      s += __shfl_xor(s, 4);
      s += __shfl_xor(s, 8);
      if (lr == 0)
        atomicAdd(out + by * 256 + wm * 128 + m * 16 + lk * 4 + i, s);
    }
  }
}

// fallback if workspace is too small: correct but slow
__global__ void k_naive(const float* __restrict__ x, const float* __restrict__ W,
                        const float* __restrict__ bs, const float* __restrict__ vb,
                        float* __restrict__ out) {
  int b = blockIdx.x;
  __shared__ float xs[1024];
  __shared__ float red[256];
  int t = threadIdx.x;
  float xsum = 0.f;
  for (int i = t; i < 1024; i += 256) { float v = x[(size_t)b * 1024 + i]; xs[i] = v; xsum += v; }
  __syncthreads();
  float tot = vb[0] * xsum;
  for (int h = t; h < 16384; h += 256) {
    int j = h >> 10, kh = h & 1023;
    float a = bs[j];
    for (int i = 0; i < 1024; ++i) a += xs[i] * W[((i + kh) & 1023) * 16 + j];
    float ax = fabsf(a);
    tot += ax + __logf(1.f + __expf(-2.f * ax)) - LN2F;
  }
  red[t] = tot;
  __syncthreads();
  for (int s2 = 128; s2; s2 >>= 1) { if (t < s2) red[t] += red[t + s2]; __syncthreads(); }
  if (t == 0) out[b] = red[0];
}

extern "C" void kernel_launch(void* const* d_in, const int* in_sizes, int n_in,
                              void* d_out, int out_size, void* d_ws, size_t ws_size,
                              hipStream_t stream) {
  const float* x  = (const float*)d_in[0];
  const float* W  = (const float*)d_in[1];
  const float* bs = (const float*)d_in[2];
  const float* vb = (const float*)d_in[3];
  float* out = (float*)d_out;

  hipMemsetAsync(d_out, 0, (size_t)out_size * sizeof(float), stream);

  size_t need = ((size_t)8 << 20) + ((size_t)32 << 20);
  if (ws_size < need) {
    k_naive<<<4096, 256, 0, stream>>>(x, W, bs, vb, out);
    return;
  }

  __bf16* Xb = (__bf16*)d_ws;
  __bf16* Kb = (__bf16*)((char*)d_ws + ((size_t)8 << 20));

  k_cvt_x<<<2048, 256, 0, stream>>>(x, vb, Xb, out);
  k_expand<<<8192, 256, 0, stream>>>(W, Kb);

  k_gemm_lc3<<<1024, 512, 0, stream>>>(Xb, Kb, bs, out);
}

// Round 4
// 182.073 us; speedup vs baseline: 1.2935x; 1.1713x over previous
//
#include <hip/hip_runtime.h>
#include <hip/hip_bf16.h>

typedef __attribute__((ext_vector_type(8))) __bf16 bf16x8;
typedef __attribute__((ext_vector_type(4))) float f32x4;

#define LN2F 0.6931471805599453f

__device__ __forceinline__ void gload16(const void* g, void* l) {
  __builtin_amdgcn_global_load_lds(
      (const __attribute__((address_space(1))) void*)g,
      (__attribute__((address_space(3))) void*)l, 16, 0, 0);
}

// ---------------------------------------------------------------------------
// Global bf16 layouts:
//   Xb: 32 mtiles x 16 ktiles, tile = 128 rows x 64 k = 8192 elems, in-tile
//       elem off = r*64 + ((s*8) ^ ((r&7)<<3))   (16B-granule XOR swizzle)
//   Kb: 128 ntiles x 16 ktiles, same in-tile layout (rows = output cols).
// ---------------------------------------------------------------------------

__global__ void k_cvt_x(const float* __restrict__ x, const float* __restrict__ vbias,
                        __bf16* __restrict__ Xb, float* __restrict__ out) {
  int t = threadIdx.x;
  int row = blockIdx.x * 2 + (t >> 7);
  int slot = t & 127;
  const float4* xp = (const float4*)(x + (size_t)row * 1024 + (size_t)slot * 8);
  float4 v0 = xp[0], v1 = xp[1];
  bf16x8 h;
  h[0] = (__bf16)v0.x; h[1] = (__bf16)v0.y; h[2] = (__bf16)v0.z; h[3] = (__bf16)v0.w;
  h[4] = (__bf16)v1.x; h[5] = (__bf16)v1.y; h[6] = (__bf16)v1.z; h[7] = (__bf16)v1.w;
  int kt = slot >> 3, si = slot & 7;
  int r = row & 127;
  size_t off = ((size_t)((row >> 7) * 16 + kt)) * 8192 + (size_t)r * 64 + ((si * 8) ^ ((r & 7) << 3));
  *(bf16x8*)(Xb + off) = h;
  float s = v0.x + v0.y + v0.z + v0.w + v1.x + v1.y + v1.z + v1.w;
  #pragma unroll
  for (int m = 32; m; m >>= 1) s += __shfl_down(s, m);
  if ((t & 63) == 0) atomicAdd(out + row, vbias[0] * s);
}

// expand via LDS-staged W column + aligned b128 reads + uniform short-shift.
// block handles 32 consecutive h (same j). LW[i] = bf16(W[(kh0+i)&1023][j]).
#define SH_(a) ((wd[a] >> 16) | (wd[(a) + 1] << 16))
#define MK4_(a) make_uint4(wd[a], wd[(a) + 1], wd[(a) + 2], wd[(a) + 3])
#define MKS_(a) make_uint4(SH_(a), SH_((a) + 1), SH_((a) + 2), SH_((a) + 3))

__global__ void k_expand2(const float* __restrict__ W, __bf16* __restrict__ Kb) {
  __shared__ __align__(16) unsigned short LW[1064];
  int h0 = blockIdx.x * 32;
  int j = h0 >> 10;
  int kh0 = h0 & 1023;             // block's kh base (multiple of 32)
  int tid = threadIdx.x;
  for (int i = tid; i < 1056; i += 256) {
    __bf16 b = (__bf16)W[((kh0 + i) & 1023) * 16 + j];
    LW[i] = *(unsigned short*)&b;
  }
  __syncthreads();
  int wv = tid >> 6, lane = tid & 63;
  #pragma unroll
  for (int hi = 0; hi < 8; ++hi) {
    int h = h0 + hi * 4 + wv;      // wave-uniform
    int kh = h & 1023;
    int c = kh & 7;                // short-granular shift, wave-uniform
    int base_e = (kh & ~7) - kh0;
    #pragma unroll
    for (int sl = 0; sl < 2; ++sl) {
      int s = lane + sl * 64;
      int i0 = (s >> 3) * 64 + (s & 7) * 8;
      const uint4* p = (const uint4*)(LW + base_e + i0);
      uint4 q0 = p[0], q1 = p[1];
      uint wd[8] = {q0.x, q0.y, q0.z, q0.w, q1.x, q1.y, q1.z, q1.w};
      uint4 o;
      switch (c) {
        case 0: o = MK4_(0); break;
        case 1: o = MKS_(0); break;
        case 2: o = MK4_(1); break;
        case 3: o = MKS_(1); break;
        case 4: o = MK4_(2); break;
        case 5: o = MKS_(2); break;
        case 6: o = MK4_(3); break;
        default: o = MKS_(3); break;
      }
      int r = h & 127;
      size_t off = ((size_t)((h >> 7) * 16 + (s >> 3))) * 8192 + (size_t)r * 64 +
                   (((s & 7) * 8) ^ ((r & 7) << 3));
      *(uint4*)(Kb + off) = o;
    }
  }
}

// GEMM 256x256x64, 512 thr = 8 waves (2M x 4N), per-wave 128x64.
// Single barrier per K-tile; reads issued in consumption order so the DS pipe
// streams under the MFMA clusters; all ds_reads are [vgpr + imm] (precomputed
// bases, K-loop unrolled x2 so buf index is compile-time).
__global__ __launch_bounds__(512, 2) void k_gemm_lc4(
    const __bf16* __restrict__ Xb, const __bf16* __restrict__ Kb,
    const float* __restrict__ bsymm, float* __restrict__ out) {
  __shared__ __align__(16) __bf16 As[32768];   // 2 buf x 16384
  __shared__ __align__(16) __bf16 Bs[32768];

  int hw = blockIdx.x;
  int wg = (hw & 7) * 128 + (hw >> 3);   // XCD swizzle (1024 % 8 == 0)
  int by = wg & 15, bx = wg >> 4;
  int tid = threadIdx.x, w = tid >> 6, lane = tid & 63;
  int wm = w >> 2, wn = w & 3;
  int lr = lane & 15, lk = lane >> 4;

  const __bf16* ga[4]; const __bf16* gb[4];   // advance 8192 elems / K-tile
  {
    const __bf16* a0 = Xb + ((size_t)(2 * by) * 16) * 8192 + w * 512 + lane * 8;
    const __bf16* a1 = Xb + ((size_t)(2 * by + 1) * 16) * 8192 + w * 512 + lane * 8;
    ga[0] = a0; ga[1] = a0 + 4096; ga[2] = a1; ga[3] = a1 + 4096;
    const __bf16* b0 = Kb + ((size_t)(2 * bx) * 16) * 8192 + w * 512 + lane * 8;
    const __bf16* b1 = Kb + ((size_t)(2 * bx + 1) * 16) * 8192 + w * 512 + lane * 8;
    gb[0] = b0; gb[1] = b0 + 4096; gb[2] = b1; gb[3] = b1 + 4096;
  }
  const __bf16 *pa[2][2], *pb[2][2];          // [buf][kh] LDS read bases
  {
    int lx0 = lr * 64 + ((lk * 8) ^ ((lr & 7) << 3));
    int lx1 = lr * 64 + (((4 + lk) * 8) ^ ((lr & 7) << 3));
    pa[0][0] = As + wm * 8192 + lx0;  pa[0][1] = As + wm * 8192 + lx1;
    pa[1][0] = pa[0][0] + 16384;      pa[1][1] = pa[0][1] + 16384;
    int bo = (wn >> 1) * 8192 + (wn & 1) * 4096;
    pb[0][0] = Bs + bo + lx0;         pb[0][1] = Bs + bo + lx1;
    pb[1][0] = pb[0][0] + 16384;      pb[1][1] = pb[0][1] + 16384;
  }

  f32x4 acc[8][4] = {};

#define STAGE(BUF) do { \
    gload16(ga[0], As + (BUF) * 16384 + w * 512); \
    gload16(ga[1], As + (BUF) * 16384 + w * 512 + 4096); \
    gload16(ga[2], As + (BUF) * 16384 + 8192 + w * 512); \
    gload16(ga[3], As + (BUF) * 16384 + 8192 + w * 512 + 4096); \
    gload16(gb[0], Bs + (BUF) * 16384 + w * 512); \
    gload16(gb[1], Bs + (BUF) * 16384 + w * 512 + 4096); \
    gload16(gb[2], Bs + (BUF) * 16384 + 8192 + w * 512); \
    gload16(gb[3], Bs + (BUF) * 16384 + 8192 + w * 512 + 4096); \
    ga[0] += 8192; ga[1] += 8192; ga[2] += 8192; ga[3] += 8192; \
    gb[0] += 8192; gb[1] += 8192; gb[2] += 8192; gb[3] += 8192; \
  } while (0)

#define TILE(BUF, PREF) do { \
    bf16x8 bfr[4][2], af[4][2]; \
    _Pragma("unroll") for (int n = 0; n < 4; ++n) { \
      bfr[n][0] = *(const bf16x8*)(pb[BUF][0] + n * 1024); \
      bfr[n][1] = *(const bf16x8*)(pb[BUF][1] + n * 1024); } \
    _Pragma("unroll") for (int m = 0; m < 4; ++m) { \
      af[m][0] = *(const bf16x8*)(pa[BUF][0] + m * 1024); \
      af[m][1] = *(const bf16x8*)(pa[BUF][1] + m * 1024); } \
    if (PREF) STAGE((BUF) ^ 1); \
    __builtin_amdgcn_s_setprio(1); \
    _Pragma("unroll") for (int m = 0; m < 4; ++m) \
      _Pragma("unroll") for (int n = 0; n < 4; ++n) { \
        acc[m][n] = __builtin_amdgcn_mfma_f32_16x16x32_bf16(af[m][0], bfr[n][0], acc[m][n], 0, 0, 0); \
        acc[m][n] = __builtin_amdgcn_mfma_f32_16x16x32_bf16(af[m][1], bfr[n][1], acc[m][n], 0, 0, 0); } \
    __builtin_amdgcn_s_setprio(0); \
    _Pragma("unroll") for (int m = 0; m < 4; ++m) { \
      af[m][0] = *(const bf16x8*)(pa[BUF][0] + 4096 + m * 1024); \
      af[m][1] = *(const bf16x8*)(pa[BUF][1] + 4096 + m * 1024); } \
    __builtin_amdgcn_s_setprio(1); \
    _Pragma("unroll") for (int m = 0; m < 4; ++m) \
      _Pragma("unroll") for (int n = 0; n < 4; ++n) { \
        acc[4 + m][n] = __builtin_amdgcn_mfma_f32_16x16x32_bf16(af[m][0], bfr[n][0], acc[4 + m][n], 0, 0, 0); \
        acc[4 + m][n] = __builtin_amdgcn_mfma_f32_16x16x32_bf16(af[m][1], bfr[n][1], acc[4 + m][n], 0, 0, 0); } \
    __builtin_amdgcn_s_setprio(0); \
    asm volatile("s_waitcnt lgkmcnt(0)" ::: "memory"); \
    if (PREF) { asm volatile("s_waitcnt vmcnt(0)" ::: "memory"); } \
    __builtin_amdgcn_sched_barrier(0); \
    __builtin_amdgcn_s_barrier(); \
  } while (0)

  STAGE(0);
  asm volatile("s_waitcnt vmcnt(0)" ::: "memory");
  __builtin_amdgcn_sched_barrier(0);
  __builtin_amdgcn_s_barrier();

  #pragma unroll 1
  for (int tt = 0; tt < 7; ++tt) { TILE(0, 1); TILE(1, 1); }
  TILE(0, 1);
  TILE(1, 0);

#undef TILE
#undef STAGE

  // epilogue: bias + logcosh + reduce over wave's 64 cols, atomicAdd per row
  float bias = bsymm[bx >> 2];
  #pragma unroll
  for (int m = 0; m < 8; ++m) {
    float rs[4] = {0.f, 0.f, 0.f, 0.f};
    #pragma unroll
    for (int n = 0; n < 4; ++n)
      #pragma unroll
      for (int i = 0; i < 4; ++i) {
        float v = acc[m][n][i] + bias;
        float ax = fabsf(v);
        rs[i] += ax + __logf(1.0f + __expf(-2.0f * ax));
      }
    #pragma unroll
    for (int i = 0; i < 4; ++i) {
      float s = rs[i] - 4.0f * LN2F;
      s += __shfl_xor(s, 1);
      s += __shfl_xor(s, 2);
      s += __shfl_xor(s, 4);
      s += __shfl_xor(s, 8);
      if (lr == 0)
        atomicAdd(out + by * 256 + wm * 128 + m * 16 + lk * 4 + i, s);
    }
  }
}

// fallback if workspace is too small: correct but slow
__global__ void k_naive(const float* __restrict__ x, const float* __restrict__ W,
                        const float* __restrict__ bs, const float* __restrict__ vb,
                        float* __restrict__ out) {
  int b = blockIdx.x;
  __shared__ float xs[1024];
  __shared__ float red[256];
  int t = threadIdx.x;
  float xsum = 0.f;
  for (int i = t; i < 1024; i += 256) { float v = x[(size_t)b * 1024 + i]; xs[i] = v; xsum += v; }
  __syncthreads();
  float tot = vb[0] * xsum;
  for (int h = t; h < 16384; h += 256) {
    int j = h >> 10, kh = h & 1023;
    float a = bs[j];
    for (int i = 0; i < 1024; ++i) a += xs[i] * W[((i + kh) & 1023) * 16 + j];
    float ax = fabsf(a);
    tot += ax + __logf(1.f + __expf(-2.f * ax)) - LN2F;
  }
  red[t] = tot;
  __syncthreads();
  for (int s2 = 128; s2; s2 >>= 1) { if (t < s2) red[t] += red[t + s2]; __syncthreads(); }
  if (t == 0) out[b] = red[0];
}

extern "C" void kernel_launch(void* const* d_in, const int* in_sizes, int n_in,
                              void* d_out, int out_size, void* d_ws, size_t ws_size,
                              hipStream_t stream) {
  const float* x  = (const float*)d_in[0];
  const float* W  = (const float*)d_in[1];
  const float* bs = (const float*)d_in[2];
  const float* vb = (const float*)d_in[3];
  float* out = (float*)d_out;

  hipMemsetAsync(d_out, 0, (size_t)out_size * sizeof(float), stream);

  size_t need = ((size_t)8 << 20) + ((size_t)32 << 20);
  if (ws_size < need) {
    k_naive<<<4096, 256, 0, stream>>>(x, W, bs, vb, out);
    return;
  }

  __bf16* Xb = (__bf16*)d_ws;
  __bf16* Kb = (__bf16*)((char*)d_ws + ((size_t)8 << 20));

  k_cvt_x<<<2048, 256, 0, stream>>>(x, vb, Xb, out);
  k_expand2<<<512, 256, 0, stream>>>(W, Kb);

  k_gemm_lc4<<<1024, 512, 0, stream>>>(Xb, Kb, bs, out);
}

// Round 5
// 179.788 us; speedup vs baseline: 1.3100x; 1.0127x over previous
//
#include <hip/hip_runtime.h>
#include <hip/hip_bf16.h>

typedef __attribute__((ext_vector_type(8))) __bf16 bf16x8;
typedef __attribute__((ext_vector_type(4))) float f32x4;

#define LN2F 0.6931471805599453f

__device__ __forceinline__ void gload16(const void* g, void* l) {
  __builtin_amdgcn_global_load_lds(
      (const __attribute__((address_space(1))) void*)g,
      (__attribute__((address_space(3))) void*)l, 16, 0, 0);
}

// ---------------------------------------------------------------------------
// Global bf16 layouts:
//   Xb: 32 mtiles x 16 ktiles, tile = 128 rows x 64 k = 8192 elems, in-tile
//       elem off = r*64 + ((s*8) ^ ((r&7)<<3))   (16B-granule XOR swizzle)
//   Kb: 128 ntiles x 16 ktiles, same in-tile layout (rows = output cols).
// ---------------------------------------------------------------------------

__global__ void k_cvt_x(const float* __restrict__ x, const float* __restrict__ vbias,
                        __bf16* __restrict__ Xb, float* __restrict__ out) {
  int t = threadIdx.x;
  int row = blockIdx.x * 2 + (t >> 7);
  int slot = t & 127;
  const float4* xp = (const float4*)(x + (size_t)row * 1024 + (size_t)slot * 8);
  float4 v0 = xp[0], v1 = xp[1];
  bf16x8 h;
  h[0] = (__bf16)v0.x; h[1] = (__bf16)v0.y; h[2] = (__bf16)v0.z; h[3] = (__bf16)v0.w;
  h[4] = (__bf16)v1.x; h[5] = (__bf16)v1.y; h[6] = (__bf16)v1.z; h[7] = (__bf16)v1.w;
  int kt = slot >> 3, si = slot & 7;
  int r = row & 127;
  size_t off = ((size_t)((row >> 7) * 16 + kt)) * 8192 + (size_t)r * 64 + ((si * 8) ^ ((r & 7) << 3));
  *(bf16x8*)(Xb + off) = h;
  float s = v0.x + v0.y + v0.z + v0.w + v1.x + v1.y + v1.z + v1.w;
  #pragma unroll
  for (int m = 32; m; m >>= 1) s += __shfl_down(s, m);
  if ((t & 63) == 0) atomicAdd(out + row, vbias[0] * s);
}

// expand via LDS-staged W column + aligned b128 reads + uniform short-shift.
#define SH_(a) ((wd[a] >> 16) | (wd[(a) + 1] << 16))
#define MK4_(a) make_uint4(wd[a], wd[(a) + 1], wd[(a) + 2], wd[(a) + 3])
#define MKS_(a) make_uint4(SH_(a), SH_((a) + 1), SH_((a) + 2), SH_((a) + 3))

__global__ void k_expand2(const float* __restrict__ W, __bf16* __restrict__ Kb) {
  __shared__ __align__(16) unsigned short LW[1064];
  int h0 = blockIdx.x * 32;
  int j = h0 >> 10;
  int kh0 = h0 & 1023;
  int tid = threadIdx.x;
  for (int i = tid; i < 1056; i += 256) {
    __bf16 b = (__bf16)W[((kh0 + i) & 1023) * 16 + j];
    LW[i] = *(unsigned short*)&b;
  }
  __syncthreads();
  int wv = tid >> 6, lane = tid & 63;
  #pragma unroll
  for (int hi = 0; hi < 8; ++hi) {
    int h = h0 + hi * 4 + wv;
    int kh = h & 1023;
    int c = kh & 7;
    int base_e = (kh & ~7) - kh0;
    #pragma unroll
    for (int sl = 0; sl < 2; ++sl) {
      int s = lane + sl * 64;
      int i0 = (s >> 3) * 64 + (s & 7) * 8;
      const uint4* p = (const uint4*)(LW + base_e + i0);
      uint4 q0 = p[0], q1 = p[1];
      uint wd[8] = {q0.x, q0.y, q0.z, q0.w, q1.x, q1.y, q1.z, q1.w};
      uint4 o;
      switch (c) {
        case 0: o = MK4_(0); break;
        case 1: o = MKS_(0); break;
        case 2: o = MK4_(1); break;
        case 3: o = MKS_(1); break;
        case 4: o = MK4_(2); break;
        case 5: o = MKS_(2); break;
        case 6: o = MK4_(3); break;
        default: o = MKS_(3); break;
      }
      int r = h & 127;
      size_t off = ((size_t)((h >> 7) * 16 + (s >> 3))) * 8192 + (size_t)r * 64 +
                   (((s & 7) * 8) ^ ((r & 7) << 3));
      *(uint4*)(Kb + off) = o;
    }
  }
}

// GEMM 256x256x64, 512 thr = 8 waves (2M x 4N), per-wave 128x64.
// 4 MFMA clusters of 16 per K-tile, each gated on only its own 4-8 ds_reads
// (fine-grained lgkmcnt) so the DS pipe streams under the MFMA clusters.
// STAGE issued at tile top (pinned by sched_barrier) -> end-of-tile vmcnt(0)
// is satisfied-on-arrival.
__global__ __launch_bounds__(512, 2) void k_gemm_lc5(
    const __bf16* __restrict__ Xb, const __bf16* __restrict__ Kb,
    const float* __restrict__ bsymm, float* __restrict__ out) {
  __shared__ __align__(16) __bf16 As[32768];   // 2 buf x 16384
  __shared__ __align__(16) __bf16 Bs[32768];

  int hw = blockIdx.x;
  int wg = (hw & 7) * 128 + (hw >> 3);   // XCD swizzle (1024 % 8 == 0)
  int by = wg & 15, bx = wg >> 4;
  int tid = threadIdx.x, w = tid >> 6, lane = tid & 63;
  int wm = w >> 2, wn = w & 3;
  int lr = lane & 15, lk = lane >> 4;

  const __bf16* ga[4]; const __bf16* gb[4];   // advance 8192 elems / K-tile
  {
    const __bf16* a0 = Xb + ((size_t)(2 * by) * 16) * 8192 + w * 512 + lane * 8;
    const __bf16* a1 = Xb + ((size_t)(2 * by + 1) * 16) * 8192 + w * 512 + lane * 8;
    ga[0] = a0; ga[1] = a0 + 4096; ga[2] = a1; ga[3] = a1 + 4096;
    const __bf16* b0 = Kb + ((size_t)(2 * bx) * 16) * 8192 + w * 512 + lane * 8;
    const __bf16* b1 = Kb + ((size_t)(2 * bx + 1) * 16) * 8192 + w * 512 + lane * 8;
    gb[0] = b0; gb[1] = b0 + 4096; gb[2] = b1; gb[3] = b1 + 4096;
  }
  const __bf16 *pa[2][2], *pb[2][2];          // [buf][kh] LDS read bases
  {
    int lx0 = lr * 64 + ((lk * 8) ^ ((lr & 7) << 3));
    int lx1 = lr * 64 + (((4 + lk) * 8) ^ ((lr & 7) << 3));
    pa[0][0] = As + wm * 8192 + lx0;  pa[0][1] = As + wm * 8192 + lx1;
    pa[1][0] = pa[0][0] + 16384;      pa[1][1] = pa[0][1] + 16384;
    int bo = (wn >> 1) * 8192 + (wn & 1) * 4096;
    pb[0][0] = Bs + bo + lx0;         pb[0][1] = Bs + bo + lx1;
    pb[1][0] = pb[0][0] + 16384;      pb[1][1] = pb[0][1] + 16384;
  }

  f32x4 acc[8][4] = {};

#define STAGE(BUF) do { \
    gload16(ga[0], As + (BUF) * 16384 + w * 512); \
    gload16(ga[1], As + (BUF) * 16384 + w * 512 + 4096); \
    gload16(ga[2], As + (BUF) * 16384 + 8192 + w * 512); \
    gload16(ga[3], As + (BUF) * 16384 + 8192 + w * 512 + 4096); \
    gload16(gb[0], Bs + (BUF) * 16384 + w * 512); \
    gload16(gb[1], Bs + (BUF) * 16384 + w * 512 + 4096); \
    gload16(gb[2], Bs + (BUF) * 16384 + 8192 + w * 512); \
    gload16(gb[3], Bs + (BUF) * 16384 + 8192 + w * 512 + 4096); \
    ga[0] += 8192; ga[1] += 8192; ga[2] += 8192; ga[3] += 8192; \
    gb[0] += 8192; gb[1] += 8192; gb[2] += 8192; gb[3] += 8192; \
  } while (0)

#define MFMA_CL(AOFF, A, B) do { \
    __builtin_amdgcn_s_setprio(1); \
    _Pragma("unroll") for (int m = 0; m < 4; ++m) \
      _Pragma("unroll") for (int n = 0; n < 4; ++n) \
        acc[(AOFF) + m][n] = __builtin_amdgcn_mfma_f32_16x16x32_bf16( \
            A[m], B[n], acc[(AOFF) + m][n], 0, 0, 0); \
    __builtin_amdgcn_s_setprio(0); \
  } while (0)

#define TILE(BUF, PREF) do { \
    bf16x8 a0[4], a1[4], a2[4], a3[4], b0[4], b1[4]; \
    _Pragma("unroll") for (int n = 0; n < 4; ++n) \
      b0[n] = *(const bf16x8*)(pb[BUF][0] + n * 1024); \
    _Pragma("unroll") for (int m = 0; m < 4; ++m) \
      a0[m] = *(const bf16x8*)(pa[BUF][0] + m * 1024); \
    if (PREF) STAGE((BUF) ^ 1); \
    __builtin_amdgcn_sched_barrier(0); /* pin stage early; C00 only needs the 8 reads above */ \
    _Pragma("unroll") for (int n = 0; n < 4; ++n) \
      b1[n] = *(const bf16x8*)(pb[BUF][1] + n * 1024); \
    _Pragma("unroll") for (int m = 0; m < 4; ++m) \
      a1[m] = *(const bf16x8*)(pa[BUF][1] + m * 1024); \
    MFMA_CL(0, a0, b0); \
    _Pragma("unroll") for (int m = 0; m < 4; ++m) \
      a2[m] = *(const bf16x8*)(pa[BUF][0] + 4096 + m * 1024); \
    MFMA_CL(0, a1, b1); \
    _Pragma("unroll") for (int m = 0; m < 4; ++m) \
      a3[m] = *(const bf16x8*)(pa[BUF][1] + 4096 + m * 1024); \
    MFMA_CL(4, a2, b0); \
    MFMA_CL(4, a3, b1); \
    asm volatile("s_waitcnt lgkmcnt(0)" ::: "memory"); \
    if (PREF) { asm volatile("s_waitcnt vmcnt(0)" ::: "memory"); } \
    __builtin_amdgcn_sched_barrier(0); \
    __builtin_amdgcn_s_barrier(); \
  } while (0)

  STAGE(0);
  asm volatile("s_waitcnt vmcnt(0)" ::: "memory");
  __builtin_amdgcn_sched_barrier(0);
  __builtin_amdgcn_s_barrier();

  #pragma unroll 1
  for (int tt = 0; tt < 7; ++tt) { TILE(0, 1); TILE(1, 1); }
  TILE(0, 1);
  TILE(1, 0);

#undef TILE
#undef MFMA_CL
#undef STAGE

  // epilogue: bias + logcosh + reduce over wave's 64 cols, atomicAdd per row
  float bias = bsymm[bx >> 2];
  #pragma unroll
  for (int m = 0; m < 8; ++m) {
    float rs[4] = {0.f, 0.f, 0.f, 0.f};
    #pragma unroll
    for (int n = 0; n < 4; ++n)
      #pragma unroll
      for (int i = 0; i < 4; ++i) {
        float v = acc[m][n][i] + bias;
        float ax = fabsf(v);
        rs[i] += ax + __logf(1.0f + __expf(-2.0f * ax));
      }
    #pragma unroll
    for (int i = 0; i < 4; ++i) {
      float s = rs[i] - 4.0f * LN2F;
      s += __shfl_xor(s, 1);
      s += __shfl_xor(s, 2);
      s += __shfl_xor(s, 4);
      s += __shfl_xor(s, 8);
      if (lr == 0)
        atomicAdd(out + by * 256 + wm * 128 + m * 16 + lk * 4 + i, s);
    }
  }
}

// fallback if workspace is too small: correct but slow
__global__ void k_naive(const float* __restrict__ x, const float* __restrict__ W,
                        const float* __restrict__ bs, const float* __restrict__ vb,
                        float* __restrict__ out) {
  int b = blockIdx.x;
  __shared__ float xs[1024];
  __shared__ float red[256];
  int t = threadIdx.x;
  float xsum = 0.f;
  for (int i = t; i < 1024; i += 256) { float v = x[(size_t)b * 1024 + i]; xs[i] = v; xsum += v; }
  __syncthreads();
  float tot = vb[0] * xsum;
  for (int h = t; h < 16384; h += 256) {
    int j = h >> 10, kh = h & 1023;
    float a = bs[j];
    for (int i = 0; i < 1024; ++i) a += xs[i] * W[((i + kh) & 1023) * 16 + j];
    float ax = fabsf(a);
    tot += ax + __logf(1.f + __expf(-2.f * ax)) - LN2F;
  }
  red[t] = tot;
  __syncthreads();
  for (int s2 = 128; s2; s2 >>= 1) { if (t < s2) red[t] += red[t + s2]; __syncthreads(); }
  if (t == 0) out[b] = red[0];
}

extern "C" void kernel_launch(void* const* d_in, const int* in_sizes, int n_in,
                              void* d_out, int out_size, void* d_ws, size_t ws_size,
                              hipStream_t stream) {
  const float* x  = (const float*)d_in[0];
  const float* W  = (const float*)d_in[1];
  const float* bs = (const float*)d_in[2];
  const float* vb = (const float*)d_in[3];
  float* out = (float*)d_out;

  hipMemsetAsync(d_out, 0, (size_t)out_size * sizeof(float), stream);

  size_t need = ((size_t)8 << 20) + ((size_t)32 << 20);
  if (ws_size < need) {
    k_naive<<<4096, 256, 0, stream>>>(x, W, bs, vb, out);
    return;
  }

  __bf16* Xb = (__bf16*)d_ws;
  __bf16* Kb = (__bf16*)((char*)d_ws + ((size_t)8 << 20));

  k_cvt_x<<<2048, 256, 0, stream>>>(x, vb, Xb, out);
  k_expand2<<<512, 256, 0, stream>>>(W, Kb);

  k_gemm_lc5<<<1024, 512, 0, stream>>>(Xb, Kb, bs, out);
}